// Round 1
// baseline (372.820 us; speedup 1.0000x reference)
//
#include <hip/hip_runtime.h>

#define NROIS 512
#define CH    256
#define HH    128
#define WW    128
#define PP    7
#define SCALE 0.0625f
#define GAMMA 0.1f

// 4-byte-aligned pair: x0f may be odd, so do not imply 8B alignment.
struct __attribute__((packed, aligned(4))) f2 { float x, y; };

__global__ __launch_bounds__(256) void dcn_pool_kernel(
    const float* __restrict__ x, const float* __restrict__ rois,
    const float* __restrict__ offs, float* __restrict__ out)
{
    const int bin = blockIdx.x;          // 0 .. 512*49-1
    const int n   = bin / 49;
    const int pq  = bin - n * 49;
    const int ph  = pq / 7;
    const int pw  = pq - ph * 7;

    // Uniform per-block ROI parameters (compiler scalarizes these loads).
    const float* r = rois + n * 5;
    const int   b  = (int)r[0];
    const float x1 = r[1] * SCALE - 0.5f;
    const float y1 = r[2] * SCALE - 0.5f;
    const float x2 = r[3] * SCALE - 0.5f;
    const float y2 = r[4] * SCALE - 0.5f;
    const float rw = fmaxf(x2 - x1, 1.0f);
    const float rh = fmaxf(y2 - y1, 1.0f);
    const float bw = rw * (1.0f / PP);
    const float bh = rh * (1.0f / PP);
    const float offx = GAMMA * rw * offs[n * 98 + pq];
    const float offy = GAMMA * rh * offs[n * 98 + 49 + pq];
    const float xb = x1 + pw * bw + offx;
    const float yb = y1 + ph * bh + offy;

    const int tid    = threadIdx.x;
    const int lane   = tid & 63;
    const int waveId = tid >> 6;
    const int idx    = lane & 31;   // 16 samples x 2 rows
    const int s      = idx >> 1;    // sample 0..15
    const int rrow   = idx & 1;     // 0: top row (y0), 1: bottom row (y1i)
    const int chHalf = lane >> 5;   // which of the 2 channels this half-wave owns

    const int   iy = s >> 2, ix = s & 3;
    const float ys = yb + ((float)iy + 0.5f) * 0.25f * bh;
    const float xs = xb + ((float)ix + 0.5f) * 0.25f * bw;
    const bool  valid = (ys > -1.0f) & (ys < (float)HH) & (xs > -1.0f) & (xs < (float)WW);
    const float yc = fminf(fmaxf(ys, 0.0f), (float)(HH - 1));
    const float xc = fminf(fmaxf(xs, 0.0f), (float)(WW - 1));
    const int   y0 = (int)floorf(yc);
    const int   x0 = (int)floorf(xc);
    const float ly = yc - (float)y0;
    const float lx = xc - (float)x0;
    const int   y1i = min(y0 + 1, HH - 1);
    const int   x0f = min(x0, WW - 2);          // pair load at (yr, x0f), (yr, x0f+1)
    const int   yr  = rrow ? y1i : y0;
    const float wy  = rrow ? ly : (1.0f - ly);

    float wA, wB;
    if (x0 <= WW - 2) { wA = 1.0f - lx; wB = lx; }   // normal: pair = (x0, x1i)
    else              { wA = 0.0f;      wB = 1.0f; } // right-edge clamp: both taps at x=127
    const float wyv = valid ? wy * (1.0f / 16.0f) : 0.0f;  // fold validity + mean/16
    wA *= wyv;
    wB *= wyv;

    const int po = yr * WW + x0f;  // offset within a channel plane; po+1 <= 16383
    const float* plane0 = x + ((size_t)(b * CH) << 14) + po;

    const int cbase = waveId * 64;  // this wave's 64 channels
    float res = 0.0f;
    #pragma unroll
    for (int i = 0; i < 32; ++i) {
        const int c = cbase + 2 * i + chHalf;
        const f2  v = *(const f2*)(plane0 + ((size_t)c << 14));
        float p = wA * v.x + wB * v.y;
        // butterfly within each 32-lane half (one channel per half)
        p += __shfl_xor(p, 1);
        p += __shfl_xor(p, 2);
        p += __shfl_xor(p, 4);
        p += __shfl_xor(p, 8);
        p += __shfl_xor(p, 16);
        const float q    = __shfl_xor(p, 32);               // other half's channel sum
        const float mine = ((lane & 1) == chHalf) ? p : q;  // pick channel cbase+2i+(lane&1)
        if ((lane >> 1) == i) res = mine;                   // lane j keeps channel cbase+j
    }

    // out[n][c][ph][pw], c = cbase + lane
    out[((size_t)(n * CH + cbase + lane)) * 49 + pq] = res;
}

extern "C" void kernel_launch(void* const* d_in, const int* in_sizes, int n_in,
                              void* d_out, int out_size, void* d_ws, size_t ws_size,
                              hipStream_t stream) {
    const float* x    = (const float*)d_in[0];
    const float* rois = (const float*)d_in[1];
    const float* offs = (const float*)d_in[2];
    float*       out  = (float*)d_out;
    dcn_pool_kernel<<<NROIS * 49, 256, 0, stream>>>(x, rois, offs, out);
}

// Round 3
// 194.102 us; speedup vs baseline: 1.9207x; 1.9207x over previous
//
#include <hip/hip_runtime.h>

#define NROIS 512
#define CH    256
#define HH    128
#define WW    128
#define SCALE 0.0625f
#define GAMMA 0.1f

// Transposed copy of x: (B,C,H,W) -> (B,H,W,C). 4*128*128*256 floats = 64 MiB.
#define XT_BYTES ((size_t)4 * 128 * 128 * 256 * 4)

// ---------------------------------------------------------------------------
// Kernel 1: tiled transpose per batch: 256 (C) x 16384 (HW)  ->  16384 x 256
// ---------------------------------------------------------------------------
__global__ __launch_bounds__(256) void transpose_kernel(
    const float* __restrict__ x, float* __restrict__ xt)
{
    __shared__ float tile[64][65];           // +1 pad: conflict-free transpose
    const int bid = blockIdx.x;              // 256 p-tiles * 4 c-tiles * 4 batches
    const int pt  = bid & 255;
    const int ct  = (bid >> 8) & 3;
    const int b   = bid >> 10;
    const int p0  = pt * 64, c0 = ct * 64;
    const size_t boff = (size_t)b * (256 * 16384);
    const int tx = threadIdx.x & 63, ty = threadIdx.x >> 6;

    #pragma unroll
    for (int i = 0; i < 16; ++i) {           // coalesced reads along HW
        const int cr = i * 4 + ty;
        tile[cr][tx] = x[boff + (size_t)(c0 + cr) * 16384 + p0 + tx];
    }
    __syncthreads();
    #pragma unroll
    for (int i = 0; i < 16; ++i) {           // coalesced writes along C
        const int pr = i * 4 + ty;
        xt[boff + (size_t)(p0 + pr) * 256 + c0 + tx] = tile[tx][pr];
    }
}

// ---------------------------------------------------------------------------
// Kernel 2: one block per (roi, 64-channel group). Lanes = channels ->
// every bilinear tap is a coalesced 256B load from the transposed layout.
// bin = waveId + 4k -> sample coords are wave-uniform (scalarized).
// Output staged in LDS, written as contiguous float4 stores.
// ---------------------------------------------------------------------------
__global__ __launch_bounds__(256) void dcn_pool_xt_kernel(
    const float* __restrict__ xt, const float* __restrict__ rois,
    const float* __restrict__ offs, float* __restrict__ out)
{
    __shared__ __align__(16) float res[64 * 49];   // 12.5 KB
    const int bid = blockIdx.x;
    const int n   = bid >> 2;
    const int g   = bid & 3;
    const int cb  = g << 6;

    const float* r = rois + n * 5;
    const int   b  = (int)r[0];
    const float x1 = r[1] * SCALE - 0.5f;
    const float y1 = r[2] * SCALE - 0.5f;
    const float rw = fmaxf(r[3] * SCALE - 0.5f - x1, 1.0f);
    const float rh = fmaxf(r[4] * SCALE - 0.5f - y1, 1.0f);
    const float bw = rw * (1.0f / 7.0f);
    const float bh = rh * (1.0f / 7.0f);

    const int c    = threadIdx.x & 63;
    const int slot = threadIdx.x >> 6;       // == waveId: bin is wave-uniform
    const float* base = xt + ((size_t)b << 22) + cb + c;

    for (int bin = slot; bin < 49; bin += 4) {
        const int ph = bin / 7, pw = bin - ph * 7;
        const float offx = GAMMA * rw * offs[n * 98 + bin];
        const float offy = GAMMA * rh * offs[n * 98 + 49 + bin];
        const float xb = x1 + pw * bw + offx;
        const float yb = y1 + ph * bh + offy;

        float acc = 0.0f;
        #pragma unroll
        for (int s = 0; s < 16; ++s) {
            const int   iy = s >> 2, ix = s & 3;
            const float ys = yb + ((float)iy + 0.5f) * 0.25f * bh;
            const float xs = xb + ((float)ix + 0.5f) * 0.25f * bw;
            const bool  valid = (ys > -1.0f) & (ys < 128.0f) &
                                (xs > -1.0f) & (xs < 128.0f);
            const float yc = fminf(fmaxf(ys, 0.0f), 127.0f);
            const float xc = fminf(fmaxf(xs, 0.0f), 127.0f);
            const int   y0 = (int)yc;        // yc >= 0 -> trunc == floor
            const int   x0 = (int)xc;
            const float ly = yc - (float)y0, lx = xc - (float)x0;
            const float hy = 1.0f - ly,      hx = 1.0f - lx;
            const int   y1i = min(y0 + 1, 127), x1i = min(x0 + 1, 127);
            const float wv = valid ? (1.0f / 16.0f) : 0.0f;   // fold valid + mean

            const int p00 = (y0 * 128 + x0)  << 8;
            const int p01 = (y0 * 128 + x1i) << 8;
            const int p10 = (y1i * 128 + x0) << 8;
            const int p11 = (y1i * 128 + x1i) << 8;
            acc += wv * (hy * (hx * base[p00] + lx * base[p01]) +
                         ly * (hx * base[p10] + lx * base[p11]));
        }
        res[c * 49 + bin] = acc;             // stride 49 (odd) -> conflict-free
    }
    __syncthreads();

    // Contiguous 3136-float span: out + (n*256+cb)*49, written as float4.
    float*        ob = out + (size_t)(n * 256 + cb) * 49;
    const float4* rs = (const float4*)res;
    float4*       od = (float4*)ob;
    for (int i = threadIdx.x; i < 784; i += 256) od[i] = rs[i];
}

// ---------------------------------------------------------------------------
// Fallback (round-1 kernel) if d_ws is too small for the transposed copy.
// ---------------------------------------------------------------------------
struct __attribute__((packed, aligned(4))) f2 { float x, y; };

__global__ __launch_bounds__(256) void dcn_pool_kernel(
    const float* __restrict__ x, const float* __restrict__ rois,
    const float* __restrict__ offs, float* __restrict__ out)
{
    const int bin = blockIdx.x;
    const int n   = bin / 49;
    const int pq  = bin - n * 49;
    const int ph  = pq / 7;
    const int pw  = pq - ph * 7;

    const float* r = rois + n * 5;
    const int   b  = (int)r[0];
    const float x1 = r[1] * SCALE - 0.5f;
    const float y1 = r[2] * SCALE - 0.5f;
    const float x2 = r[3] * SCALE - 0.5f;
    const float y2 = r[4] * SCALE - 0.5f;
    const float rw = fmaxf(x2 - x1, 1.0f);
    const float rh = fmaxf(y2 - y1, 1.0f);
    const float bw = rw * (1.0f / 7.0f);
    const float bh = rh * (1.0f / 7.0f);
    const float offx = GAMMA * rw * offs[n * 98 + pq];
    const float offy = GAMMA * rh * offs[n * 98 + 49 + pq];
    const float xb = x1 + pw * bw + offx;
    const float yb = y1 + ph * bh + offy;

    const int tid    = threadIdx.x;
    const int lane   = tid & 63;
    const int waveId = tid >> 6;
    const int idx    = lane & 31;
    const int s      = idx >> 1;
    const int rrow   = idx & 1;
    const int chHalf = lane >> 5;

    const int   iy = s >> 2, ix = s & 3;
    const float ys = yb + ((float)iy + 0.5f) * 0.25f * bh;
    const float xs = xb + ((float)ix + 0.5f) * 0.25f * bw;
    const bool  valid = (ys > -1.0f) & (ys < 128.0f) & (xs > -1.0f) & (xs < 128.0f);
    const float yc = fminf(fmaxf(ys, 0.0f), 127.0f);
    const float xc = fminf(fmaxf(xs, 0.0f), 127.0f);
    const int   y0 = (int)floorf(yc);
    const int   x0 = (int)floorf(xc);
    const float ly = yc - (float)y0;
    const float lx = xc - (float)x0;
    const int   y1i = min(y0 + 1, 127);
    const int   x0f = min(x0, 126);
    const int   yr  = rrow ? y1i : y0;
    const float wy  = rrow ? ly : (1.0f - ly);

    float wA, wB;
    if (x0 <= 126) { wA = 1.0f - lx; wB = lx; }
    else           { wA = 0.0f;      wB = 1.0f; }
    const float wyv = valid ? wy * (1.0f / 16.0f) : 0.0f;
    wA *= wyv;
    wB *= wyv;

    const int po = yr * 128 + x0f;
    const float* plane0 = x + ((size_t)(b * 256) << 14) + po;

    const int cbase = waveId * 64;
    float resv = 0.0f;
    #pragma unroll
    for (int i = 0; i < 32; ++i) {
        const int c = cbase + 2 * i + chHalf;
        const f2  v = *(const f2*)(plane0 + ((size_t)c << 14));
        float p = wA * v.x + wB * v.y;
        p += __shfl_xor(p, 1);
        p += __shfl_xor(p, 2);
        p += __shfl_xor(p, 4);
        p += __shfl_xor(p, 8);
        p += __shfl_xor(p, 16);
        const float q    = __shfl_xor(p, 32);
        const float mine = ((lane & 1) == chHalf) ? p : q;
        if ((lane >> 1) == i) resv = mine;
    }
    out[((size_t)(n * 256 + cbase + lane)) * 49 + pq] = resv;
}

extern "C" void kernel_launch(void* const* d_in, const int* in_sizes, int n_in,
                              void* d_out, int out_size, void* d_ws, size_t ws_size,
                              hipStream_t stream) {
    const float* x    = (const float*)d_in[0];
    const float* rois = (const float*)d_in[1];
    const float* offs = (const float*)d_in[2];
    float*       out  = (float*)d_out;

    if (ws_size >= XT_BYTES) {
        float* xt = (float*)d_ws;
        transpose_kernel<<<4096, 256, 0, stream>>>(x, xt);
        dcn_pool_xt_kernel<<<NROIS * 4, 256, 0, stream>>>(xt, rois, offs, out);
    } else {
        dcn_pool_kernel<<<NROIS * 49, 256, 0, stream>>>(x, rois, offs, out);
    }
}